// Round 9
// baseline (136.644 us; speedup 1.0000x reference)
//
#include <hip/hip_runtime.h>
#include <stdint.h>

typedef _Float16 half8 __attribute__((ext_vector_type(8)));
typedef _Float16 half4 __attribute__((ext_vector_type(4)));
typedef __fp16   fp16x2 __attribute__((ext_vector_type(2)));
typedef float    floatx4 __attribute__((ext_vector_type(4)));
typedef unsigned uintx2 __attribute__((ext_vector_type(2)));

#define T_LEN 2048
#define CH 64
#define BH 32            // bs * n_heads
#define QTILE 128        // t per block (16 per wave, 8 waves) -> 512 blocks
#define LDP 72           // prep LDS pad (halves)
#define FRAG_BH 131072   // halves per bh per tensor (64*2048)

// ---------------- pass 1: fp32 -> fp16, reorder into MFMA fragment order ----------
// Q pre-scaled by 0.125 * rescale * log2(e) so attention does raw exp2.
// QF/KF[bh][g][ks][lane][8]: g = t(or s)>>4, element = X[c = ks*32+quad*8+j][t = g*16+l15]
// VF[bh][sl][ct][lane][4]  (16x16x16 A-frag order):
//   element = V[c = ct*16 + l15][s = sl*16 + quad*4 + e]
__global__ __launch_bounds__(256, 2)
void prep_kernel(const float* __restrict__ qkv, const float* __restrict__ rescale,
                 _Float16* __restrict__ ws)
{
    __shared__ _Float16 Qs[64][LDP];   // [t][c]
    __shared__ _Float16 Ks[64][LDP];   // [s][c]
    __shared__ _Float16 Vs[64][LDP];   // [c][s]

    const int tid  = threadIdx.x;
    const int bh   = blockIdx.y;
    const int tile = blockIdx.x;       // 64-element tile along t/s
    const int x0   = tile * 64;

    const float qscale = 0.125f * 1.4426950408889634f * rescale[0];

    const float* qp = qkv + (size_t)(bh >> 3) * (1536 * T_LEN)
                          + (size_t)(bh & 7) * (192 * T_LEN);
    const float* kp = qp + 64 * T_LEN;
    const float* vp = qp + 128 * T_LEN;

    // Q,K: 4x4 register-block transpose [c][t] -> [t][c]
    {
        const int a4 = (tid & 15) * 4;
        const int c4 = (tid >> 4) * 4;
        float4 rq[4], rk[4];
#pragma unroll
        for (int i = 0; i < 4; ++i) {
            rq[i] = *(const float4*)(qp + (size_t)(c4 + i) * T_LEN + x0 + a4);
            rk[i] = *(const float4*)(kp + (size_t)(c4 + i) * T_LEN + x0 + a4);
        }
#pragma unroll
        for (int j = 0; j < 4; ++j) {
            half4 hq, hk;
#pragma unroll
            for (int i = 0; i < 4; ++i) {
                hq[i] = (_Float16)((&rq[i].x)[j] * qscale);
                hk[i] = (_Float16)((&rk[i].x)[j]);
            }
            *(half4*)&Qs[a4 + j][c4] = hq;
            *(half4*)&Ks[a4 + j][c4] = hk;
        }
        // V natural [c][s]
        const int s4 = (tid & 15) * 4;
        const int cv = tid >> 4;
#pragma unroll
        for (int i = 0; i < 4; ++i) {
            const int c = cv + 16 * i;
            float4 r = *(const float4*)(vp + (size_t)c * T_LEN + x0 + s4);
            half4 h; h[0]=(_Float16)r.x; h[1]=(_Float16)r.y; h[2]=(_Float16)r.z; h[3]=(_Float16)r.w;
            *(half4*)&Vs[c][s4] = h;
        }
    }
    __syncthreads();

    const int lane = tid & 63, wave = tid >> 6;
    const int l15 = lane & 15, quad = lane >> 4;
    _Float16* qf = ws;
    _Float16* kf = ws + (size_t)BH * FRAG_BH;
    _Float16* vf = ws + (size_t)2 * BH * FRAG_BH;

#pragma unroll
    for (int ks = 0; ks < 2; ++ks) {
        half8 hq = *(const half8*)&Qs[wave * 16 + l15][ks * 32 + quad * 8];
        half8 hk = *(const half8*)&Ks[wave * 16 + l15][ks * 32 + quad * 8];
        const size_t gqk = (((size_t)bh * 128 + tile * 4 + wave) * 2 + ks) * 512 + lane * 8;
        *(half8*)(qf + gqk) = hq;
        *(half8*)(kf + gqk) = hk;
    }
    // V fragments: wave w handles sl = tile*4 + w (16 s values)
#pragma unroll
    for (int ct = 0; ct < 4; ++ct) {
        half4 hv = *(const half4*)&Vs[ct * 16 + l15][wave * 16 + quad * 4];
        *(half4*)(vf + (size_t)bh * FRAG_BH
                     + ((size_t)(tile * 4 + wave) * 4 + ct) * 256 + lane * 4) = hv;
    }
}

// async global->LDS, 16B per lane: dest = lds_base(uniform) + lane*16
__device__ __forceinline__ void gload16(const _Float16* g, _Float16* l) {
    __builtin_amdgcn_global_load_lds(
        (const __attribute__((address_space(1))) void*)g,
        (__attribute__((address_space(3))) void*)l, 16, 0, 0);
}

// ---------------- pass 2: attention, 8-wave blocks, in-register softmax -----------
// R8 post-mortem: conflicts=0, Pt deleted, still 52.9us. Correct per-SIMD math:
// MFMA 16x16x32 = ~19.4 cy/SIMD (2075TF / 1024 SIMDs), so per wave-tile matrix
// work = ~660cy; at 2 waves/SIMD = 1320cy demand vs 3578cy measured tile-window
// = 37% = measured MfmaUtil exactly. Not a stall mystery: NOT ENOUGH INDEPENDENT
// WAVES per SIMD to interleave the serial QK->exp->PV chains. R2/R7 refuted
// "more waves" only when waves multiplied TRAFFIC (private streams / more blocks).
// Unrefuted config: more waves per BLOCK sharing the same staged K/V tile.
// This round: 512-thread blocks (8 waves, 16 t each), same 512 blocks, same
// 16KB/block-iter staging (2 async insts/wave), same XCD swizzle, same R8 body.
// Per-wave state halves (oacc 16 + ak 32 + bv 32 + bq 8 ~ 100 regs < 128) ->
// __launch_bounds__(512,4) = 4 waves/SIMD at CONSTANT traffic.
__global__ __launch_bounds__(512, 4)
void attn_kernel(const _Float16* __restrict__ ws, float* __restrict__ out)
{
    __shared__ _Float16 Kb[2][4096];      // [buf][8KB tile]
    __shared__ _Float16 Vb[2][4096];

    const int tid  = threadIdx.x;
    const int wave = tid >> 6;            // 0..7
    const int lane = tid & 63;
    const int l15  = lane & 15;
    const int quad = lane >> 4;

    // XCD-aware decode: all 16 t-tiles of one bh on ONE XCD (4 bh x 512KB = 2MB/XCD L2)
    const int bid  = blockIdx.x;        // 0..511
    const int xcd  = bid & 7;
    const int slot = bid >> 3;          // 0..63
    const int bh   = (slot >> 4) * 8 + xcd;
    const int tile = slot & 15;
    const int t0   = tile * QTILE;

    const _Float16* qf = ws;
    const _Float16* kf = ws + (size_t)BH * FRAG_BH;
    const _Float16* vf = ws + (size_t)2 * BH * FRAG_BH;
    float* op = out + (size_t)bh * (CH * T_LEN);

    const _Float16* ktile = kf + (size_t)bh * FRAG_BH;   // + st*4096 per tile
    const _Float16* vtile = vf + (size_t)bh * FRAG_BH;

    // stage tile st into buf: 16KB split over 8 waves, 2 async insts/wave
    auto stage = [&](int st, int buf) {
        const _Float16* kg = ktile + (size_t)st * 4096 + wave * 512 + lane * 8;
        const _Float16* vg = vtile + (size_t)st * 4096 + wave * 512 + lane * 8;
        gload16(kg, &Kb[buf][wave * 512]);
        gload16(vg, &Vb[buf][wave * 512]);
    };

    // Q fragment: wave's 16-t group (g = tile*8 + wave), persistent
    half8 bq[2];
#pragma unroll
    for (int ks = 0; ks < 2; ++ks)
        bq[ks] = *(const half8*)(qf +
            (((size_t)bh * 128 + tile * 8 + wave) * 2 + ks) * 512 + lane * 8);

    const floatx4 fzero = {0.f, 0.f, 0.f, 0.f};
    floatx4 oacc[4];                    // [ct]; c = ct*16+quad*4+r, t = l15 (wave group)
#pragma unroll
    for (int ct = 0; ct < 4; ++ct) oacc[ct] = fzero;
    float lsum = 0.f;                   // per-lane partial denominator

    half8 ak[4][2];      // K frags of current tile (A-operand, 16x16x32)
    half4 bv[4][4];      // V frags [mt][ct] of current tile (A-operand, 16x16x16)

    auto read_ak = [&](int buf) {
#pragma unroll
        for (int mt = 0; mt < 4; ++mt)
#pragma unroll
            for (int ks = 0; ks < 2; ++ks)
                ak[mt][ks] = *(const half8*)&Kb[buf][(mt * 2 + ks) * 512 + lane * 8];
    };
    auto read_bv = [&](int buf) {
#pragma unroll
        for (int mt = 0; mt < 4; ++mt)
#pragma unroll
            for (int ct = 0; ct < 4; ++ct)
                bv[mt][ct] = *(const half4*)&Vb[buf][mt * 1024 + ct * 256 + lane * 4];
    };

    // tile st: per mt-slice QK -> in-register exp -> PV (no LDS, no shuffle)
    auto body = [&]() {
#pragma unroll
        for (int mt = 0; mt < 4; ++mt) {
            floatx4 s0 = fzero;
#pragma unroll
            for (int ks = 0; ks < 2; ++ks)
                s0 = __builtin_amdgcn_mfma_f32_16x16x32_f16(ak[mt][ks], bq[ks], s0, 0, 0, 0);
            // lane holds P[t = g*16+l15][s = st*64 + mt*16 + quad*4 + r]
            float a0 = __builtin_amdgcn_exp2f(s0[0]);
            float a1 = __builtin_amdgcn_exp2f(s0[1]);
            float a2 = __builtin_amdgcn_exp2f(s0[2]);
            float a3 = __builtin_amdgcn_exp2f(s0[3]);
            lsum += (a0 + a1) + (a2 + a3);
            uintx2 u0;
            u0[0] = __builtin_bit_cast(unsigned, __builtin_amdgcn_cvt_pkrtz(a0, a1));
            u0[1] = __builtin_bit_cast(unsigned, __builtin_amdgcn_cvt_pkrtz(a2, a3));
            half4 p0 = __builtin_bit_cast(half4, u0);   // B-frag: col=t(l15), k=quad*4+e
#pragma unroll
            for (int ct = 0; ct < 4; ++ct)
                oacc[ct] = __builtin_amdgcn_mfma_f32_16x16x16f16(
                    bv[mt][ct], p0, oacc[ct], 0, 0, 0);
        }
    };

    // ---- prologue
    stage(0, 0);
    __syncthreads();              // tile 0 in buf 0
    read_ak(0);
    read_bv(0);
    stage(1, 1);                  // full tile-0 compute to land

    // ---- main loop: one barrier per tile
    for (int st = 0; st < 32; ++st) {
        const int cur = st & 1;
        if (st >= 1 && st < 31) stage(st + 1, cur ^ 1);  // buf freed at last barrier
        body();                   // tile st from registers
        if (st < 31) {
            __syncthreads();      // tile st+1 landed; reg reads of buf cur done
            read_ak(cur ^ 1);
            read_bv(cur ^ 1);
        }
    }

    // ---- epilogue: quad-reduce denominator, scale, store (no LDS) ---------------
    float v = lsum;
    v += __shfl_xor(v, 16, 64);
    v += __shfl_xor(v, 32, 64);
    const float linv = 1.0f / v;
    // oacc[ct][r] = O[c = ct*16 + quad*4 + r][t = t0 + wave*16 + l15]
    const int t = t0 + wave * 16 + l15;
#pragma unroll
    for (int ct = 0; ct < 4; ++ct)
#pragma unroll
        for (int r = 0; r < 4; ++r)
            op[(size_t)(ct * 16 + quad * 4 + r) * T_LEN + t] = oacc[ct][r] * linv;
}

extern "C" void kernel_launch(void* const* d_in, const int* in_sizes, int n_in,
                              void* d_out, int out_size, void* d_ws, size_t ws_size,
                              hipStream_t stream) {
    const float* qkv     = (const float*)d_in[0];
    const float* rescale = (const float*)d_in[1];
    float* out = (float*)d_out;
    _Float16* ws = (_Float16*)d_ws;   // needs 3*32*131072*2 B = 25.2 MB

    prep_kernel<<<dim3(32, BH), dim3(256), 0, stream>>>(qkv, rescale, ws);
    attn_kernel<<<dim3(T_LEN / QTILE * BH), dim3(512), 0, stream>>>(ws, out);
}